// Round 1
// baseline (112.887 us; speedup 1.0000x reference)
//
#include <hip/hip_runtime.h>
#include <hip/hip_bf16.h>

typedef unsigned short u16;
typedef __attribute__((ext_vector_type(8))) short short8;
typedef __attribute__((ext_vector_type(4))) float f32x4;

#define BSZ   4096
#define INF   1024
#define FEAT  512
#define NCLS  1000
#define NPAD  1024
#define DTOT  2048

__device__ __forceinline__ u16 f2bf(float f) {
  unsigned int x = __float_as_uint(f);
  x += 0x7fffu + ((x >> 16) & 1u);   // RNE; inputs finite, no NaN path needed
  return (u16)(x >> 16);
}
__device__ __forceinline__ float bf2f(u16 h) {
  return __uint_as_float((unsigned int)h << 16);
}
__device__ __forceinline__ void gload_lds16(const void* g, void* l) {
  __builtin_amdgcn_global_load_lds(
      (const __attribute__((address_space(1))) void*)g,
      (__attribute__((address_space(3))) void*)l, 16, 0, 0);
}

// ---------------- fp32 -> bf16 elementwise convert (8 elems/thread) --------
__global__ __launch_bounds__(256) void cvt_bf16(const float* __restrict__ in,
                                                u16* __restrict__ outp, int n8) {
  int i = blockIdx.x * 256 + threadIdx.x;
  if (i >= n8) return;
  const float4* p = (const float4*)in;
  float4 a = p[2 * i], b = p[2 * i + 1];
  short8 o;
  o[0] = (short)f2bf(a.x); o[1] = (short)f2bf(a.y);
  o[2] = (short)f2bf(a.z); o[3] = (short)f2bf(a.w);
  o[4] = (short)f2bf(b.x); o[5] = (short)f2bf(b.y);
  o[6] = (short)f2bf(b.z); o[7] = (short)f2bf(b.w);
  *(short8*)&outp[(size_t)i * 8] = o;
}

// ------------- centers: convert to bf16 (padded to 1024 rows) + c2 ---------
__global__ __launch_bounds__(256) void cvt_centers(const float* __restrict__ cen,
                                                   u16* __restrict__ Cb,
                                                   float* __restrict__ c2) {
  const int row = blockIdx.x;   // 0..1023
  const int t = threadIdx.x;    // 256 threads, 8 elems each (D=2048)
  float s = 0.f;
  if (row < NCLS) {
    const float4* p = (const float4*)(cen + (size_t)row * DTOT) + 2 * t;
    float4 a = p[0], b = p[1];
    short8 o;
    o[0] = (short)f2bf(a.x); o[1] = (short)f2bf(a.y);
    o[2] = (short)f2bf(a.z); o[3] = (short)f2bf(a.w);
    o[4] = (short)f2bf(b.x); o[5] = (short)f2bf(b.y);
    o[6] = (short)f2bf(b.z); o[7] = (short)f2bf(b.w);
    *(short8*)&Cb[(size_t)row * DTOT + t * 8] = o;
    s = a.x * a.x + a.y * a.y + a.z * a.z + a.w * a.w +
        b.x * b.x + b.y * b.y + b.z * b.z + b.w * b.w;
  } else {
    short8 z = {0, 0, 0, 0, 0, 0, 0, 0};
    *(short8*)&Cb[(size_t)row * DTOT + t * 8] = z;
  }
#pragma unroll
  for (int o = 32; o > 0; o >>= 1) s += __shfl_xor(s, o);
  __shared__ float red[4];
  if ((t & 63) == 0) red[t >> 6] = s;
  __syncthreads();
  if (t == 0) c2[row] = red[0] + red[1] + red[2] + red[3];
}

// ---------------- per-row sum of squares over bf16 feat --------------------
__global__ __launch_bounds__(256) void row_sumsq(const u16* __restrict__ X,
                                                 float* __restrict__ f2) {
  const int row = blockIdx.x;
  const int t = threadIdx.x;
  short8 v = *(const short8*)&X[(size_t)row * DTOT + t * 8];
  float s = 0.f;
#pragma unroll
  for (int q = 0; q < 8; ++q) { float f = bf2f((u16)v[q]); s += f * f; }
#pragma unroll
  for (int o = 32; o > 0; o >>= 1) s += __shfl_xor(s, o);
  __shared__ float red[4];
  if ((t & 63) == 0) red[t >> 6] = s;
  __syncthreads();
  if (t == 0) f2[row] = red[0] + red[1] + red[2] + red[3];
}

// ---------------- feature GEMM: feat = relu(X @ W^T + b), bf16 -------------
// C tile 128x128, 4 waves (2x2), each wave 64x64 via 4x4 frags of 16x16x32.
__global__ __launch_bounds__(256) void feat_gemm(const u16* __restrict__ Xb,
                                                 const u16* __restrict__ Wb,
                                                 const float* __restrict__ bf_,
                                                 const float* __restrict__ br_,
                                                 u16* __restrict__ Fb) {
  __shared__ u16 As[128 * 64];
  __shared__ u16 Bs[128 * 64];
  const int t = threadIdx.x;
  const int lane = t & 63;
  const int wid = t >> 6;
  const int wr = (wid >> 1) * 64;
  const int wc = (wid & 1) * 64;
  const int bm0 = blockIdx.y * 128;
  const int gc0 = blockIdx.x * 128;      // global feat col 0..2047
  const int g = gc0 >> 9;                // quadrant 0..3
  const int bn0 = gc0 & 511;             // col within W
  const u16* A = Xb + (size_t)g * BSZ * INF;
  const u16* Bt = Wb + (size_t)(g ? 1 : 0) * FEAT * INF;
  const float* bias = g ? br_ : bf_;

  const int r8 = t >> 3;                 // staging row 0..31 (+32/it)
  const int kc = (t & 7) << 3;           // staging k col (elems)
  const int l15 = lane & 15;
  const int l4 = lane >> 4;

  f32x4 acc[4][4] = {};

  for (int k0 = 0; k0 < INF; k0 += 64) {
    __syncthreads();
#pragma unroll
    for (int it = 0; it < 4; ++it) {
      gload_lds16(&A[(size_t)(bm0 + it * 32 + r8) * INF + k0 + kc],
                  &As[(it * 256 + (wid << 6)) * 8]);
      gload_lds16(&Bt[(size_t)(bn0 + it * 32 + r8) * INF + k0 + kc],
                  &Bs[(it * 256 + (wid << 6)) * 8]);
    }
    __syncthreads();
#pragma unroll
    for (int ks = 0; ks < 2; ++ks) {
      const int ko = ks * 32 + l4 * 8;
      short8 av[4], bv[4];
#pragma unroll
      for (int i = 0; i < 4; ++i)
        av[i] = *(const short8*)&As[(wr + i * 16 + l15) * 64 + ko];
#pragma unroll
      for (int j = 0; j < 4; ++j)
        bv[j] = *(const short8*)&Bs[(wc + j * 16 + l15) * 64 + ko];
#pragma unroll
      for (int i = 0; i < 4; ++i)
#pragma unroll
        for (int j = 0; j < 4; ++j)
          acc[i][j] = __builtin_amdgcn_mfma_f32_16x16x32_bf16(av[i], bv[j],
                                                              acc[i][j], 0, 0, 0);
    }
  }

#pragma unroll
  for (int j = 0; j < 4; ++j) {
    const int col = gc0 + wc + j * 16 + l15;
    const float bval = bias[bn0 + wc + j * 16 + l15];
#pragma unroll
    for (int i = 0; i < 4; ++i) {
#pragma unroll
      for (int r = 0; r < 4; ++r) {
        const int row = bm0 + wr + i * 16 + l4 * 4 + r;
        float v = fmaxf(acc[i][j][r] + bval, 0.f);
        Fb[(size_t)row * DTOT + col] = f2bf(v);
      }
    }
  }
}

// ------- distance GEMM: out = -0.1*sqrt(max(f2 + c2 - 2*feat.c, 0)) --------
__global__ __launch_bounds__(256) void dist_gemm(const u16* __restrict__ Fb,
                                                 const u16* __restrict__ Cb,
                                                 const float* __restrict__ f2,
                                                 const float* __restrict__ c2,
                                                 float* __restrict__ out) {
  __shared__ u16 As[128 * 64];
  __shared__ u16 Bs[128 * 64];
  const int t = threadIdx.x;
  const int lane = t & 63;
  const int wid = t >> 6;
  const int wr = (wid >> 1) * 64;
  const int wc = (wid & 1) * 64;
  const int bm0 = blockIdx.y * 128;
  const int bn0 = blockIdx.x * 128;      // padded class col 0..1023

  const int r8 = t >> 3;
  const int kc = (t & 7) << 3;
  const int l15 = lane & 15;
  const int l4 = lane >> 4;

  f32x4 acc[4][4] = {};

  for (int k0 = 0; k0 < DTOT; k0 += 64) {
    __syncthreads();
#pragma unroll
    for (int it = 0; it < 4; ++it) {
      gload_lds16(&Fb[(size_t)(bm0 + it * 32 + r8) * DTOT + k0 + kc],
                  &As[(it * 256 + (wid << 6)) * 8]);
      gload_lds16(&Cb[(size_t)(bn0 + it * 32 + r8) * DTOT + k0 + kc],
                  &Bs[(it * 256 + (wid << 6)) * 8]);
    }
    __syncthreads();
#pragma unroll
    for (int ks = 0; ks < 2; ++ks) {
      const int ko = ks * 32 + l4 * 8;
      short8 av[4], bv[4];
#pragma unroll
      for (int i = 0; i < 4; ++i)
        av[i] = *(const short8*)&As[(wr + i * 16 + l15) * 64 + ko];
#pragma unroll
      for (int j = 0; j < 4; ++j)
        bv[j] = *(const short8*)&Bs[(wc + j * 16 + l15) * 64 + ko];
#pragma unroll
      for (int i = 0; i < 4; ++i)
#pragma unroll
        for (int j = 0; j < 4; ++j)
          acc[i][j] = __builtin_amdgcn_mfma_f32_16x16x32_bf16(av[i], bv[j],
                                                              acc[i][j], 0, 0, 0);
    }
  }

#pragma unroll
  for (int j = 0; j < 4; ++j) {
    const int col = bn0 + wc + j * 16 + l15;
    const float c2v = c2[col];
#pragma unroll
    for (int i = 0; i < 4; ++i) {
#pragma unroll
      for (int r = 0; r < 4; ++r) {
        const int row = bm0 + wr + i * 16 + l4 * 4 + r;
        float d2 = f2[row] + c2v - 2.f * acc[i][j][r];
        float v = -0.1f * sqrtf(fmaxf(d2, 0.f));
        if (col < NCLS) out[(size_t)row * NCLS + col] = v;
      }
    }
  }
}

extern "C" void kernel_launch(void* const* d_in, const int* in_sizes, int n_in,
                              void* d_out, int out_size, void* d_ws, size_t ws_size,
                              hipStream_t stream) {
  const float* x    = (const float*)d_in[0];
  const float* x90  = (const float*)d_in[1];
  const float* x180 = (const float*)d_in[2];
  const float* x270 = (const float*)d_in[3];
  const float* W_f  = (const float*)d_in[4];
  const float* b_f  = (const float*)d_in[5];
  const float* W_r  = (const float*)d_in[6];
  const float* b_r  = (const float*)d_in[7];
  const float* cen  = (const float*)d_in[8];
  float* out = (float*)d_out;

  // workspace layout (bf16 as u16)
  u16* Xb = (u16*)d_ws;                         // [4][4096][1024]
  u16* Wb = Xb + 4ull * BSZ * INF;              // [2][512][1024]
  u16* Cb = Wb + 2ull * FEAT * INF;             // [1024][2048]
  u16* Fb = Cb + (size_t)NPAD * DTOT;           // [4096][2048]
  float* f2 = (float*)(Fb + (size_t)BSZ * DTOT);// [4096]
  float* c2 = f2 + BSZ;                         // [1024]

  const int n8x = BSZ * INF / 8;   // 524288
  const int n8w = FEAT * INF / 8;  // 65536
  cvt_bf16<<<(n8x + 255) / 256, 256, 0, stream>>>(x, Xb, n8x);
  cvt_bf16<<<(n8x + 255) / 256, 256, 0, stream>>>(x90, Xb + 1ull * BSZ * INF, n8x);
  cvt_bf16<<<(n8x + 255) / 256, 256, 0, stream>>>(x180, Xb + 2ull * BSZ * INF, n8x);
  cvt_bf16<<<(n8x + 255) / 256, 256, 0, stream>>>(x270, Xb + 3ull * BSZ * INF, n8x);
  cvt_bf16<<<(n8w + 255) / 256, 256, 0, stream>>>(W_f, Wb, n8w);
  cvt_bf16<<<(n8w + 255) / 256, 256, 0, stream>>>(W_r, Wb + (size_t)FEAT * INF, n8w);
  cvt_centers<<<NPAD, 256, 0, stream>>>(cen, Cb, c2);

  feat_gemm<<<dim3(DTOT / 128, BSZ / 128), 256, 0, stream>>>(Xb, Wb, b_f, b_r, Fb);
  row_sumsq<<<BSZ, 256, 0, stream>>>(Fb, f2);
  dist_gemm<<<dim3(NPAD / 128, BSZ / 128), 256, 0, stream>>>(Fb, Cb, f2, c2, out);
}

// Round 2
// 97.266 us; speedup vs baseline: 1.1606x; 1.1606x over previous
//
#include <hip/hip_runtime.h>
#include <hip/hip_bf16.h>

typedef unsigned short u16;
typedef __attribute__((ext_vector_type(8))) short short8;
typedef __attribute__((ext_vector_type(4))) float f32x4;

#define BSZ   4096
#define INF   1024
#define FEAT  512
#define NCLS  1000
#define NPAD  1024
#define DTOT  2048

__device__ __forceinline__ u16 f2bf(float f) {
  unsigned int x = __float_as_uint(f);
  x += 0x7fffu + ((x >> 16) & 1u);   // RNE; inputs finite, no NaN path needed
  return (u16)(x >> 16);
}
__device__ __forceinline__ float bf2f(u16 h) {
  return __uint_as_float((unsigned int)h << 16);
}
__device__ __forceinline__ void gload_lds16(const void* g, void* l) {
  __builtin_amdgcn_global_load_lds(
      (const __attribute__((address_space(1))) void*)g,
      (__attribute__((address_space(3))) void*)l, 16, 0, 0);
}

// -------- fp32 -> bf16 convert, 4 source tensors in one dispatch -----------
__global__ __launch_bounds__(256) void cvt_bf16_x4(const float* __restrict__ x0,
                                                   const float* __restrict__ x1,
                                                   const float* __restrict__ x2,
                                                   const float* __restrict__ x3,
                                                   u16* __restrict__ outp, int n8) {
  int i = blockIdx.x * 256 + threadIdx.x;
  if (i >= n8) return;
  const float* in = (blockIdx.y & 2) ? ((blockIdx.y & 1) ? x3 : x2)
                                     : ((blockIdx.y & 1) ? x1 : x0);
  const float4* p = (const float4*)in;
  float4 a = p[2 * i], b = p[2 * i + 1];
  short8 o;
  o[0] = (short)f2bf(a.x); o[1] = (short)f2bf(a.y);
  o[2] = (short)f2bf(a.z); o[3] = (short)f2bf(a.w);
  o[4] = (short)f2bf(b.x); o[5] = (short)f2bf(b.y);
  o[6] = (short)f2bf(b.z); o[7] = (short)f2bf(b.w);
  *(short8*)&outp[(size_t)blockIdx.y * n8 * 8 + (size_t)i * 8] = o;
}

__global__ __launch_bounds__(256) void cvt_bf16(const float* __restrict__ in,
                                                u16* __restrict__ outp, int n8) {
  int i = blockIdx.x * 256 + threadIdx.x;
  if (i >= n8) return;
  const float4* p = (const float4*)in;
  float4 a = p[2 * i], b = p[2 * i + 1];
  short8 o;
  o[0] = (short)f2bf(a.x); o[1] = (short)f2bf(a.y);
  o[2] = (short)f2bf(a.z); o[3] = (short)f2bf(a.w);
  o[4] = (short)f2bf(b.x); o[5] = (short)f2bf(b.y);
  o[6] = (short)f2bf(b.z); o[7] = (short)f2bf(b.w);
  *(short8*)&outp[(size_t)i * 8] = o;
}

// ------------- centers: convert to bf16 (padded to 1024 rows) + c2 ---------
__global__ __launch_bounds__(256) void cvt_centers(const float* __restrict__ cen,
                                                   u16* __restrict__ Cb,
                                                   float* __restrict__ c2) {
  const int row = blockIdx.x;   // 0..1023
  const int t = threadIdx.x;    // 256 threads, 8 elems each (D=2048)
  float s = 0.f;
  if (row < NCLS) {
    const float4* p = (const float4*)(cen + (size_t)row * DTOT) + 2 * t;
    float4 a = p[0], b = p[1];
    short8 o;
    o[0] = (short)f2bf(a.x); o[1] = (short)f2bf(a.y);
    o[2] = (short)f2bf(a.z); o[3] = (short)f2bf(a.w);
    o[4] = (short)f2bf(b.x); o[5] = (short)f2bf(b.y);
    o[6] = (short)f2bf(b.z); o[7] = (short)f2bf(b.w);
    *(short8*)&Cb[(size_t)row * DTOT + t * 8] = o;
    s = a.x * a.x + a.y * a.y + a.z * a.z + a.w * a.w +
        b.x * b.x + b.y * b.y + b.z * b.z + b.w * b.w;
  } else {
    short8 z = {0, 0, 0, 0, 0, 0, 0, 0};
    *(short8*)&Cb[(size_t)row * DTOT + t * 8] = z;
  }
#pragma unroll
  for (int o = 32; o > 0; o >>= 1) s += __shfl_xor(s, o);
  __shared__ float red[4];
  if ((t & 63) == 0) red[t >> 6] = s;
  __syncthreads();
  if (t == 0) c2[row] = red[0] + red[1] + red[2] + red[3];
}

// ---------------- per-row sum of squares over bf16 feat --------------------
__global__ __launch_bounds__(256) void row_sumsq(const u16* __restrict__ X,
                                                 float* __restrict__ f2) {
  const int row = blockIdx.x;
  const int t = threadIdx.x;
  short8 v = *(const short8*)&X[(size_t)row * DTOT + t * 8];
  float s = 0.f;
#pragma unroll
  for (int q = 0; q < 8; ++q) { float f = bf2f((u16)v[q]); s += f * f; }
#pragma unroll
  for (int o = 32; o > 0; o >>= 1) s += __shfl_xor(s, o);
  __shared__ float red[4];
  if ((t & 63) == 0) red[t >> 6] = s;
  __syncthreads();
  if (t == 0) f2[row] = red[0] + red[1] + red[2] + red[3];
}

// ---------------- feature GEMM: feat = relu(X @ W^T + b), bf16 -------------
// C tile 128x128, 4 waves (2x2), each wave 64x64 via 4x4 frags of 16x16x32.
__global__ __launch_bounds__(256) void feat_gemm(const u16* __restrict__ Xb,
                                                 const u16* __restrict__ Wb,
                                                 const float* __restrict__ bf_,
                                                 const float* __restrict__ br_,
                                                 u16* __restrict__ Fb) {
  __shared__ u16 As[128 * 64];
  __shared__ u16 Bs[128 * 64];
  const int t = threadIdx.x;
  const int lane = t & 63;
  const int wid = t >> 6;
  const int wr = (wid >> 1) * 64;
  const int wc = (wid & 1) * 64;
  const int bm0 = blockIdx.y * 128;
  const int gc0 = blockIdx.x * 128;      // global feat col 0..2047
  const int g = gc0 >> 9;                // quadrant 0..3
  const int bn0 = gc0 & 511;             // col within W
  const u16* A = Xb + (size_t)g * BSZ * INF;
  const u16* Bt = Wb + (size_t)(g ? 1 : 0) * FEAT * INF;
  const float* bias = g ? br_ : bf_;

  const int r8 = t >> 3;                 // staging row 0..31 (+32/it)
  const int kc = (t & 7) << 3;           // staging k col (elems)
  const int l15 = lane & 15;
  const int l4 = lane >> 4;

  f32x4 acc[4][4] = {};

  for (int k0 = 0; k0 < INF; k0 += 64) {
    __syncthreads();
#pragma unroll
    for (int it = 0; it < 4; ++it) {
      gload_lds16(&A[(size_t)(bm0 + it * 32 + r8) * INF + k0 + kc],
                  &As[(it * 256 + (wid << 6)) * 8]);
      gload_lds16(&Bt[(size_t)(bn0 + it * 32 + r8) * INF + k0 + kc],
                  &Bs[(it * 256 + (wid << 6)) * 8]);
    }
    __syncthreads();
#pragma unroll
    for (int ks = 0; ks < 2; ++ks) {
      const int ko = ks * 32 + l4 * 8;
      short8 av[4], bv[4];
#pragma unroll
      for (int i = 0; i < 4; ++i)
        av[i] = *(const short8*)&As[(wr + i * 16 + l15) * 64 + ko];
#pragma unroll
      for (int j = 0; j < 4; ++j)
        bv[j] = *(const short8*)&Bs[(wc + j * 16 + l15) * 64 + ko];
#pragma unroll
      for (int i = 0; i < 4; ++i)
#pragma unroll
        for (int j = 0; j < 4; ++j)
          acc[i][j] = __builtin_amdgcn_mfma_f32_16x16x32_bf16(av[i], bv[j],
                                                              acc[i][j], 0, 0, 0);
    }
  }

#pragma unroll
  for (int j = 0; j < 4; ++j) {
    const int col = gc0 + wc + j * 16 + l15;
    const float bval = bias[bn0 + wc + j * 16 + l15];
#pragma unroll
    for (int i = 0; i < 4; ++i) {
#pragma unroll
      for (int r = 0; r < 4; ++r) {
        const int row = bm0 + wr + i * 16 + l4 * 4 + r;
        float v = fmaxf(acc[i][j][r] + bval, 0.f);
        Fb[(size_t)row * DTOT + col] = f2bf(v);
      }
    }
  }
}

// ------- distance GEMM: out = -0.1*sqrt(max(f2 + c2 - 2*feat.c, 0)) --------
// C tile 128x64 -> grid (16,32)=512 blocks = 2 blocks/CU (the 128x128 version
// gave only 256 blocks = 1 block/CU: barrier drains had nothing to overlap,
// MfmaUtil 8.6%). 4 waves (2x2), each wave 64x32 via 4x2 frags.
__global__ __launch_bounds__(256) void dist_gemm(const u16* __restrict__ Fb,
                                                 const u16* __restrict__ Cb,
                                                 const float* __restrict__ f2,
                                                 const float* __restrict__ c2,
                                                 float* __restrict__ out) {
  __shared__ u16 As[128 * 64];
  __shared__ u16 Bs[64 * 64];
  const int t = threadIdx.x;
  const int lane = t & 63;
  const int wid = t >> 6;
  const int wr = (wid >> 1) * 64;
  const int wc = (wid & 1) * 32;
  const int bm0 = blockIdx.y * 128;
  const int bn0 = blockIdx.x * 64;       // padded class col 0..1023

  const int r8 = t >> 3;
  const int kc = (t & 7) << 3;
  const int l15 = lane & 15;
  const int l4 = lane >> 4;

  f32x4 acc[4][2] = {};

  for (int k0 = 0; k0 < DTOT; k0 += 64) {
    __syncthreads();
#pragma unroll
    for (int it = 0; it < 4; ++it)
      gload_lds16(&Fb[(size_t)(bm0 + it * 32 + r8) * DTOT + k0 + kc],
                  &As[(it * 256 + (wid << 6)) * 8]);
#pragma unroll
    for (int it = 0; it < 2; ++it)
      gload_lds16(&Cb[(size_t)(bn0 + it * 32 + r8) * DTOT + k0 + kc],
                  &Bs[(it * 256 + (wid << 6)) * 8]);
    __syncthreads();
#pragma unroll
    for (int ks = 0; ks < 2; ++ks) {
      const int ko = ks * 32 + l4 * 8;
      short8 av[4], bv[2];
#pragma unroll
      for (int i = 0; i < 4; ++i)
        av[i] = *(const short8*)&As[(wr + i * 16 + l15) * 64 + ko];
#pragma unroll
      for (int j = 0; j < 2; ++j)
        bv[j] = *(const short8*)&Bs[(wc + j * 16 + l15) * 64 + ko];
#pragma unroll
      for (int i = 0; i < 4; ++i)
#pragma unroll
        for (int j = 0; j < 2; ++j)
          acc[i][j] = __builtin_amdgcn_mfma_f32_16x16x32_bf16(av[i], bv[j],
                                                              acc[i][j], 0, 0, 0);
    }
  }

#pragma unroll
  for (int j = 0; j < 2; ++j) {
    const int col = bn0 + wc + j * 16 + l15;
    const float c2v = c2[col];
#pragma unroll
    for (int i = 0; i < 4; ++i) {
#pragma unroll
      for (int r = 0; r < 4; ++r) {
        const int row = bm0 + wr + i * 16 + l4 * 4 + r;
        float d2 = f2[row] + c2v - 2.f * acc[i][j][r];
        float v = -0.1f * sqrtf(fmaxf(d2, 0.f));
        if (col < NCLS) out[(size_t)row * NCLS + col] = v;
      }
    }
  }
}

extern "C" void kernel_launch(void* const* d_in, const int* in_sizes, int n_in,
                              void* d_out, int out_size, void* d_ws, size_t ws_size,
                              hipStream_t stream) {
  const float* x    = (const float*)d_in[0];
  const float* x90  = (const float*)d_in[1];
  const float* x180 = (const float*)d_in[2];
  const float* x270 = (const float*)d_in[3];
  const float* W_f  = (const float*)d_in[4];
  const float* b_f  = (const float*)d_in[5];
  const float* W_r  = (const float*)d_in[6];
  const float* b_r  = (const float*)d_in[7];
  const float* cen  = (const float*)d_in[8];
  float* out = (float*)d_out;

  // workspace layout (bf16 as u16)
  u16* Xb = (u16*)d_ws;                         // [4][4096][1024]
  u16* Wb = Xb + 4ull * BSZ * INF;              // [2][512][1024]
  u16* Cb = Wb + 2ull * FEAT * INF;             // [1024][2048]
  u16* Fb = Cb + (size_t)NPAD * DTOT;           // [4096][2048]
  float* f2 = (float*)(Fb + (size_t)BSZ * DTOT);// [4096]
  float* c2 = f2 + BSZ;                         // [1024]

  const int n8x = BSZ * INF / 8;   // 524288
  const int n8w = FEAT * INF / 8;  // 65536
  cvt_bf16_x4<<<dim3((n8x + 255) / 256, 4), 256, 0, stream>>>(x, x90, x180, x270,
                                                              Xb, n8x);
  cvt_bf16<<<(n8w + 255) / 256, 256, 0, stream>>>(W_f, Wb, n8w);
  cvt_bf16<<<(n8w + 255) / 256, 256, 0, stream>>>(W_r, Wb + (size_t)FEAT * INF, n8w);
  cvt_centers<<<NPAD, 256, 0, stream>>>(cen, Cb, c2);

  feat_gemm<<<dim3(DTOT / 128, BSZ / 128), 256, 0, stream>>>(Xb, Wb, b_f, b_r, Fb);
  row_sumsq<<<BSZ, 256, 0, stream>>>(Fb, f2);
  dist_gemm<<<dim3(NPAD / 64, BSZ / 128), 256, 0, stream>>>(Fb, Cb, f2, c2, out);
}

// Round 3
// 89.101 us; speedup vs baseline: 1.2670x; 1.0916x over previous
//
#include <hip/hip_runtime.h>
#include <hip/hip_bf16.h>

typedef unsigned short u16;
typedef __attribute__((ext_vector_type(8))) short short8;
typedef __attribute__((ext_vector_type(4))) float f32x4;

#define BSZ   4096
#define INF   1024
#define FEAT  512
#define NCLS  1000
#define NPAD  1024
#define DTOT  2048

__device__ __forceinline__ u16 f2bf(float f) {
  unsigned int x = __float_as_uint(f);
  x += 0x7fffu + ((x >> 16) & 1u);   // RNE; inputs finite, no NaN path needed
  return (u16)(x >> 16);
}
__device__ __forceinline__ float bf2f(u16 h) {
  return __uint_as_float((unsigned int)h << 16);
}
__device__ __forceinline__ void gload_lds16(const void* g, void* l) {
  __builtin_amdgcn_global_load_lds(
      (const __attribute__((address_space(1))) void*)g,
      (__attribute__((address_space(3))) void*)l, 16, 0, 0);
}

// -------- fp32 -> bf16 convert, 4 source tensors in one dispatch -----------
__global__ __launch_bounds__(256) void cvt_bf16_x4(const float* __restrict__ x0,
                                                   const float* __restrict__ x1,
                                                   const float* __restrict__ x2,
                                                   const float* __restrict__ x3,
                                                   u16* __restrict__ outp, int n8) {
  int i = blockIdx.x * 256 + threadIdx.x;
  if (i >= n8) return;
  const float* in = (blockIdx.y & 2) ? ((blockIdx.y & 1) ? x3 : x2)
                                     : ((blockIdx.y & 1) ? x1 : x0);
  const float4* p = (const float4*)in;
  float4 a = p[2 * i], b = p[2 * i + 1];
  short8 o;
  o[0] = (short)f2bf(a.x); o[1] = (short)f2bf(a.y);
  o[2] = (short)f2bf(a.z); o[3] = (short)f2bf(a.w);
  o[4] = (short)f2bf(b.x); o[5] = (short)f2bf(b.y);
  o[6] = (short)f2bf(b.z); o[7] = (short)f2bf(b.w);
  *(short8*)&outp[(size_t)blockIdx.y * n8 * 8 + (size_t)i * 8] = o;
}

__global__ __launch_bounds__(256) void cvt_bf16(const float* __restrict__ in,
                                                u16* __restrict__ outp, int n8) {
  int i = blockIdx.x * 256 + threadIdx.x;
  if (i >= n8) return;
  const float4* p = (const float4*)in;
  float4 a = p[2 * i], b = p[2 * i + 1];
  short8 o;
  o[0] = (short)f2bf(a.x); o[1] = (short)f2bf(a.y);
  o[2] = (short)f2bf(a.z); o[3] = (short)f2bf(a.w);
  o[4] = (short)f2bf(b.x); o[5] = (short)f2bf(b.y);
  o[6] = (short)f2bf(b.z); o[7] = (short)f2bf(b.w);
  *(short8*)&outp[(size_t)i * 8] = o;
}

// ------------- centers: convert to bf16 (padded to 1024 rows) + c2 ---------
__global__ __launch_bounds__(256) void cvt_centers(const float* __restrict__ cen,
                                                   u16* __restrict__ Cb,
                                                   float* __restrict__ c2) {
  const int row = blockIdx.x;   // 0..1023
  const int t = threadIdx.x;    // 256 threads, 8 elems each (D=2048)
  float s = 0.f;
  if (row < NCLS) {
    const float4* p = (const float4*)(cen + (size_t)row * DTOT) + 2 * t;
    float4 a = p[0], b = p[1];
    short8 o;
    o[0] = (short)f2bf(a.x); o[1] = (short)f2bf(a.y);
    o[2] = (short)f2bf(a.z); o[3] = (short)f2bf(a.w);
    o[4] = (short)f2bf(b.x); o[5] = (short)f2bf(b.y);
    o[6] = (short)f2bf(b.z); o[7] = (short)f2bf(b.w);
    *(short8*)&Cb[(size_t)row * DTOT + t * 8] = o;
    s = a.x * a.x + a.y * a.y + a.z * a.z + a.w * a.w +
        b.x * b.x + b.y * b.y + b.z * b.z + b.w * b.w;
  } else {
    short8 z = {0, 0, 0, 0, 0, 0, 0, 0};
    *(short8*)&Cb[(size_t)row * DTOT + t * 8] = z;
  }
#pragma unroll
  for (int o = 32; o > 0; o >>= 1) s += __shfl_xor(s, o);
  __shared__ float red[4];
  if ((t & 63) == 0) red[t >> 6] = s;
  __syncthreads();
  if (t == 0) c2[row] = red[0] + red[1] + red[2] + red[3];
}

// ---------------- per-row sum of squares over bf16 feat --------------------
__global__ __launch_bounds__(256) void row_sumsq(const u16* __restrict__ X,
                                                 float* __restrict__ f2) {
  const int row = blockIdx.x;
  const int t = threadIdx.x;
  short8 v = *(const short8*)&X[(size_t)row * DTOT + t * 8];
  float s = 0.f;
#pragma unroll
  for (int q = 0; q < 8; ++q) { float f = bf2f((u16)v[q]); s += f * f; }
#pragma unroll
  for (int o = 32; o > 0; o >>= 1) s += __shfl_xor(s, o);
  __shared__ float red[4];
  if ((t & 63) == 0) red[t >> 6] = s;
  __syncthreads();
  if (t == 0) f2[row] = red[0] + red[1] + red[2] + red[3];
}

// ---------------- feature GEMM: feat = relu(X @ W^T + b), bf16 -------------
// C tile 128x128, 4 waves (2x2), dbuf LDS (stage t+1 || compute t), XOR
// slot-swizzle (slot ^= row&7; applied on global SOURCE + on ds_read, LDS
// dest stays linear for global_load_lds). XCD-chunked block swizzle.
__global__ __launch_bounds__(256) void feat_gemm(const u16* __restrict__ Xb,
                                                 const u16* __restrict__ Wb,
                                                 const float* __restrict__ bf_,
                                                 const float* __restrict__ br_,
                                                 u16* __restrict__ Fb) {
  __shared__ u16 As[2][128 * 64];
  __shared__ u16 Bs[2][128 * 64];
  const int t = threadIdx.x;
  const int lane = t & 63;
  const int wid = t >> 6;
  const int wr = (wid >> 1) * 64;
  const int wc = (wid & 1) * 64;
  // XCD-chunked swizzle: 512 wgs, 8 XCDs -> 64 consecutive wgs per XCD
  const int lid = blockIdx.x;
  const int swg = (lid & 7) * 64 + (lid >> 3);
  const int bm0 = (swg >> 4) * 128;      // M block (32 rows of blocks)
  const int bn  = swg & 15;              // N block 0..15
  const int gc0 = bn * 128;              // global feat col
  const int g = bn >> 2;                 // quadrant 0..3
  const int bn0 = (bn & 3) * 128;        // col within W
  const u16* A = Xb + (size_t)g * BSZ * INF;
  const u16* Bt = Wb + (g ? (size_t)FEAT * INF : 0);
  const float* bias = g ? br_ : bf_;

  const int r8 = t >> 3;                          // staging row 0..31 (+32/it)
  const int kcs = (((t & 7) ^ (r8 & 7)) << 3);    // swizzled source slot
  const int l15 = lane & 15;
  const int l4 = lane >> 4;
  const int swz = l15 & 7;

  f32x4 acc[4][4] = {};

  auto stage = [&](int buf, int k0) {
#pragma unroll
    for (int it = 0; it < 4; ++it) {
      gload_lds16(&A[(size_t)(bm0 + it * 32 + r8) * INF + k0 + kcs],
                  &As[buf][(it * 256 + (wid << 6)) * 8]);
      gload_lds16(&Bt[(size_t)(bn0 + it * 32 + r8) * INF + k0 + kcs],
                  &Bs[buf][(it * 256 + (wid << 6)) * 8]);
    }
  };
  auto comp = [&](int buf) {
#pragma unroll
    for (int ks = 0; ks < 2; ++ks) {
      const int so = (((ks * 4 + l4) ^ swz) << 3);
      short8 av[4], bv[4];
#pragma unroll
      for (int i = 0; i < 4; ++i)
        av[i] = *(const short8*)&As[buf][(wr + i * 16 + l15) * 64 + so];
#pragma unroll
      for (int j = 0; j < 4; ++j)
        bv[j] = *(const short8*)&Bs[buf][(wc + j * 16 + l15) * 64 + so];
#pragma unroll
      for (int i = 0; i < 4; ++i)
#pragma unroll
        for (int j = 0; j < 4; ++j)
          acc[i][j] = __builtin_amdgcn_mfma_f32_16x16x32_bf16(av[i], bv[j],
                                                              acc[i][j], 0, 0, 0);
    }
  };

  stage(0, 0);
  __syncthreads();
  for (int k0 = 0; k0 < INF; k0 += 128) {
    stage(1, k0 + 64);
    comp(0);
    __syncthreads();
    if (k0 + 128 < INF) stage(0, k0 + 128);
    comp(1);
    __syncthreads();
  }

#pragma unroll
  for (int j = 0; j < 4; ++j) {
    const int col = gc0 + wc + j * 16 + l15;
    const float bval = bias[bn0 + wc + j * 16 + l15];
#pragma unroll
    for (int i = 0; i < 4; ++i) {
#pragma unroll
      for (int r = 0; r < 4; ++r) {
        const int row = bm0 + wr + i * 16 + l4 * 4 + r;
        float v = fmaxf(acc[i][j][r] + bval, 0.f);
        Fb[(size_t)row * DTOT + col] = f2bf(v);
      }
    }
  }
}

// ------- distance GEMM: out = -0.1*sqrt(max(f2 + c2 - 2*feat.c, 0)) --------
// C tile 128x64 (512 blocks = 2/CU), dbuf + swizzle as feat_gemm.
__global__ __launch_bounds__(256) void dist_gemm(const u16* __restrict__ Fb,
                                                 const u16* __restrict__ Cb,
                                                 const float* __restrict__ f2,
                                                 const float* __restrict__ c2,
                                                 float* __restrict__ out) {
  __shared__ u16 As[2][128 * 64];
  __shared__ u16 Bs[2][64 * 64];
  const int t = threadIdx.x;
  const int lane = t & 63;
  const int wid = t >> 6;
  const int wr = (wid >> 1) * 64;
  const int wc = (wid & 1) * 32;
  const int lid = blockIdx.x;
  const int swg = (lid & 7) * 64 + (lid >> 3);
  const int bm0 = (swg >> 4) * 128;
  const int bn0 = (swg & 15) * 64;       // padded class col

  const int r8 = t >> 3;
  const int kcs = (((t & 7) ^ (r8 & 7)) << 3);
  const int l15 = lane & 15;
  const int l4 = lane >> 4;
  const int swz = l15 & 7;

  f32x4 acc[4][2] = {};

  auto stage = [&](int buf, int k0) {
#pragma unroll
    for (int it = 0; it < 4; ++it)
      gload_lds16(&Fb[(size_t)(bm0 + it * 32 + r8) * DTOT + k0 + kcs],
                  &As[buf][(it * 256 + (wid << 6)) * 8]);
#pragma unroll
    for (int it = 0; it < 2; ++it)
      gload_lds16(&Cb[(size_t)(bn0 + it * 32 + r8) * DTOT + k0 + kcs],
                  &Bs[buf][(it * 256 + (wid << 6)) * 8]);
  };
  auto comp = [&](int buf) {
#pragma unroll
    for (int ks = 0; ks < 2; ++ks) {
      const int so = (((ks * 4 + l4) ^ swz) << 3);
      short8 av[4], bv[2];
#pragma unroll
      for (int i = 0; i < 4; ++i)
        av[i] = *(const short8*)&As[buf][(wr + i * 16 + l15) * 64 + so];
#pragma unroll
      for (int j = 0; j < 2; ++j)
        bv[j] = *(const short8*)&Bs[buf][(wc + j * 16 + l15) * 64 + so];
#pragma unroll
      for (int i = 0; i < 4; ++i)
#pragma unroll
        for (int j = 0; j < 2; ++j)
          acc[i][j] = __builtin_amdgcn_mfma_f32_16x16x32_bf16(av[i], bv[j],
                                                              acc[i][j], 0, 0, 0);
    }
  };

  stage(0, 0);
  __syncthreads();
  for (int k0 = 0; k0 < DTOT; k0 += 128) {
    stage(1, k0 + 64);
    comp(0);
    __syncthreads();
    if (k0 + 128 < DTOT) stage(0, k0 + 128);
    comp(1);
    __syncthreads();
  }

#pragma unroll
  for (int j = 0; j < 2; ++j) {
    const int col = bn0 + wc + j * 16 + l15;
    const float c2v = c2[col];
#pragma unroll
    for (int i = 0; i < 4; ++i) {
#pragma unroll
      for (int r = 0; r < 4; ++r) {
        const int row = bm0 + wr + i * 16 + l4 * 4 + r;
        float d2 = f2[row] + c2v - 2.f * acc[i][j][r];
        float v = -0.1f * sqrtf(fmaxf(d2, 0.f));
        if (col < NCLS) out[(size_t)row * NCLS + col] = v;
      }
    }
  }
}

extern "C" void kernel_launch(void* const* d_in, const int* in_sizes, int n_in,
                              void* d_out, int out_size, void* d_ws, size_t ws_size,
                              hipStream_t stream) {
  const float* x    = (const float*)d_in[0];
  const float* x90  = (const float*)d_in[1];
  const float* x180 = (const float*)d_in[2];
  const float* x270 = (const float*)d_in[3];
  const float* W_f  = (const float*)d_in[4];
  const float* b_f  = (const float*)d_in[5];
  const float* W_r  = (const float*)d_in[6];
  const float* b_r  = (const float*)d_in[7];
  const float* cen  = (const float*)d_in[8];
  float* out = (float*)d_out;

  // workspace layout (bf16 as u16)
  u16* Xb = (u16*)d_ws;                         // [4][4096][1024]
  u16* Wb = Xb + 4ull * BSZ * INF;              // [2][512][1024]
  u16* Cb = Wb + 2ull * FEAT * INF;             // [1024][2048]
  u16* Fb = Cb + (size_t)NPAD * DTOT;           // [4096][2048]
  float* f2 = (float*)(Fb + (size_t)BSZ * DTOT);// [4096]
  float* c2 = f2 + BSZ;                         // [1024]

  const int n8x = BSZ * INF / 8;   // 524288
  const int n8w = FEAT * INF / 8;  // 65536
  cvt_bf16_x4<<<dim3((n8x + 255) / 256, 4), 256, 0, stream>>>(x, x90, x180, x270,
                                                              Xb, n8x);
  cvt_bf16<<<(n8w + 255) / 256, 256, 0, stream>>>(W_f, Wb, n8w);
  cvt_bf16<<<(n8w + 255) / 256, 256, 0, stream>>>(W_r, Wb + (size_t)FEAT * INF, n8w);
  cvt_centers<<<NPAD, 256, 0, stream>>>(cen, Cb, c2);

  feat_gemm<<<512, 256, 0, stream>>>(Xb, Wb, b_f, b_r, Fb);
  row_sumsq<<<BSZ, 256, 0, stream>>>(Fb, f2);
  dist_gemm<<<512, 256, 0, stream>>>(Fb, Cb, f2, c2, out);
}